// Round 10
// baseline (328.803 us; speedup 1.0000x reference)
//
#include <hip/hip_runtime.h>
#include <hip/hip_bf16.h>

#define HWN   4096
#define CIN   256
#define NINTER 128
#define NBATCH 4
#define BN_EPS 1e-5f
#define NC    4          // key chunks for attention pass 1
#define CHUNK 1024       // keys per chunk
#define LOG2E 1.4426950408889634f
#define SMAX  64.0f      // fixed softmax max (base-2 units; row max ~55 worst-case)

typedef __bf16 bf16_t;
typedef __bf16 bf16x8 __attribute__((ext_vector_type(8)));
typedef __bf16 bf16x4 __attribute__((ext_vector_type(4)));
typedef float  f32x4  __attribute__((ext_vector_type(4)));
typedef float  f32x16 __attribute__((ext_vector_type(16)));

__device__ __forceinline__ float fexp2(float x) {
  return __builtin_amdgcn_exp2f(x);
}

__device__ __forceinline__ void split_bf16(float v, bf16_t& h, bf16_t& l) {
  h = (bf16_t)v;
  l = (bf16_t)(v - (float)h);
}

// load 8 fp32 and split into hi/lo bf16x8
__device__ __forceinline__ void load_split8(const float* p, bf16x8& h, bf16x8& l) {
  f32x4 a = *(const f32x4*)p;
  f32x4 b = *(const f32x4*)(p + 4);
#pragma unroll
  for (int j = 0; j < 4; j++) {
    bf16_t hh, ll;
    split_bf16(a[j], hh, ll);
    h[j] = hh; l[j] = ll;
    split_bf16(b[j], hh, ll);
    h[4 + j] = hh; l[4 + j] = ll;
  }
}

// load 8 fp32, round to bf16x8
__device__ __forceinline__ bf16x8 load_cvt8(const float* p) {
  f32x4 a = *(const f32x4*)p;
  f32x4 b = *(const f32x4*)(p + 4);
  bf16x8 r;
#pragma unroll
  for (int j = 0; j < 4; j++) {
    r[j] = (bf16_t)a[j];
    r[4 + j] = (bf16_t)b[j];
  }
  return r;
}

// Workspace (bytes): QH 4M, KH 4M, V 4M, OP fp32 32M, WY bf16 8M,
// LP 256K, ST 2K. Total ~54.8 MB. (OP and WY both live in wconv -> disjoint.)
#define OFF_QH  0
#define OFF_KH  4194304
#define OFF_V   8388608
#define OFF_OP  12582912
#define OFF_WY  46137344
#define OFF_LP  54525952
#define OFF_ST  54788096

// Fused QKV conv (+fp32 weight convert in-register, +ST zeroing).
// n-tile 32, grid (128, 4). Q scaled by log2(e), single bf16.
__global__ __launch_bounds__(256, 4) void qkv_kernel(
    const float* __restrict__ x,
    const float* __restrict__ tw, const float* __restrict__ pw,
    const float* __restrict__ gw,
    const float* __restrict__ tb, const float* __restrict__ pb,
    const float* __restrict__ gb,
    bf16_t* __restrict__ Qh, bf16_t* __restrict__ Kh, bf16_t* __restrict__ V,
    float* __restrict__ ST) {
  const int ntb  = blockIdx.x;   // 128 tiles of 32 n
  const int b    = blockIdx.y;
  const int tid  = threadIdx.x;
  const int lane = tid & 63;
  const int wv   = tid >> 6;
  const int l31  = lane & 31;
  const int half = lane >> 5;

  // zero the stats accumulator for this call (stream-ordered before wconv)
  if (ntb == 0 && b == 0 && tid < 512) ST[tid] = 0.f;

  __shared__ __align__(16) bf16_t smem[4608];            // 9216 B
  bf16_t (*xTh)[72] = (bf16_t(*)[72])smem;               // [32][72]
  bf16_t (*xTl)[72] = (bf16_t(*)[72])(smem + 2304);      // [32][72]
  bf16_t (*Tr)[136] = (bf16_t(*)[136])smem;              // [32][136] (reuse)

  const float* xb = x + (size_t)b * CIN * HWN + ntb * 32;

  f32x16 aq, ak, av;
#pragma unroll
  for (int i = 0; i < 16; i++) { aq[i] = 0.f; ak[i] = 0.f; av[i] = 0.f; }

  for (int c0 = 0; c0 < 256; c0 += 64) {
    __syncthreads();
#pragma unroll
    for (int i = 0; i < 8; i++) {         // 2048 elements: 64c x 32n
      int idx = tid + i * 256;
      int cc = idx >> 5;
      int nn = idx & 31;
      float v = xb[(size_t)(c0 + cc) * HWN + nn];
      bf16_t h, l;
      split_bf16(v, h, l);
      xTh[nn][cc] = h;
      xTl[nn][cc] = l;
    }
    __syncthreads();
#pragma unroll
    for (int kk = 0; kk < 64; kk += 16) {
      size_t woff = (size_t)(32 * wv + l31) * 256 + c0 + kk + half * 8;
      bf16x8 th, tl, ph, pl;
      load_split8(tw + woff, th, tl);
      load_split8(pw + woff, ph, pl);
      bf16x8 gh = load_cvt8(gw + woff);
      bf16x8 bh = *(const bf16x8*)(&xTh[l31][kk + half * 8]);
      bf16x8 bl = *(const bf16x8*)(&xTl[l31][kk + half * 8]);
      aq = __builtin_amdgcn_mfma_f32_32x32x16_bf16(th, bh, aq, 0, 0, 0);
      aq = __builtin_amdgcn_mfma_f32_32x32x16_bf16(th, bl, aq, 0, 0, 0);
      aq = __builtin_amdgcn_mfma_f32_32x32x16_bf16(tl, bh, aq, 0, 0, 0);
      ak = __builtin_amdgcn_mfma_f32_32x32x16_bf16(ph, bh, ak, 0, 0, 0);
      ak = __builtin_amdgcn_mfma_f32_32x32x16_bf16(ph, bl, ak, 0, 0, 0);
      ak = __builtin_amdgcn_mfma_f32_32x32x16_bf16(pl, bh, ak, 0, 0, 0);
      av = __builtin_amdgcn_mfma_f32_32x32x16_bf16(gh, bh, av, 0, 0, 0);
    }
  }

  // ---- epilogue: 2 LDS-transpose rounds (Qh, Kh) + direct V store ----
  const int trow = tid >> 3;          // 0..31
  const int tc16 = (tid & 7) * 16;    // 0..112
  bf16_t* qh = Qh + ((size_t)b * HWN + ntb * 32) * NINTER;
  bf16_t* kh = Kh + ((size_t)b * HWN + ntb * 32) * NINTER;

#pragma unroll
  for (int rnd = 0; rnd < 2; rnd++) {
    __syncthreads();
#pragma unroll
    for (int rg = 0; rg < 4; rg++) {
      int och0 = 32 * wv + 8 * rg + 4 * half;
#pragma unroll
      for (int j = 0; j < 4; j++) {
        float v = (rnd == 0) ? (aq[rg * 4 + j] + tb[och0 + j]) * LOG2E
                             : (ak[rg * 4 + j] + pb[och0 + j]);
        Tr[l31][och0 + j] = (bf16_t)v;
      }
    }
    __syncthreads();
    bf16_t* dst = (rnd == 0) ? qh : kh;
    bf16x8 v0 = *(const bf16x8*)(&Tr[trow][tc16]);
    bf16x8 v1 = *(const bf16x8*)(&Tr[trow][tc16 + 8]);
    *(bf16x8*)(dst + (size_t)trow * NINTER + tc16) = v0;
    *(bf16x8*)(dst + (size_t)trow * NINTER + tc16 + 8) = v1;
  }

  const int n = ntb * 32 + l31;
  bf16_t* vd = V + (size_t)b * NINTER * HWN;
#pragma unroll
  for (int r = 0; r < 16; r++) {
    int och = 32 * wv + (r & 3) + 8 * (r >> 2) + 4 * half;
    vd[(size_t)och * HWN + n] = (bf16_t)(av[r] + gb[och]);
  }
}

// Flash attention pass 1 (unchanged from R9): fixed-max softmax, single-Q.
// Block = 128 q rows (4 waves x 32 q), 32 K-tiles of 32 keys.
// grid (32 qt, 4 chunk, 4 b) = 512 blocks = 2/CU.
__global__ __launch_bounds__(256, 2) void attn_kernel(
    const bf16_t* __restrict__ Qh, const bf16_t* __restrict__ Kh,
    const bf16_t* __restrict__ V,
    float* __restrict__ Opart, float* __restrict__ Lp) {
  const int qt    = blockIdx.x;
  const int chunk = blockIdx.y;
  const int b     = blockIdx.z;
  const int tid   = threadIdx.x;
  const int lane  = tid & 63;
  const int wv    = tid >> 6;
  const int l15   = lane & 15;
  const int quad  = lane >> 4;
  const int kbase = chunk * CHUNK;

  __shared__ __align__(16) bf16_t Klds[32][136];   // 8704 B
  __shared__ __align__(16) bf16_t Vlds[144][56];   // 16128 B (row 128: ones; 129+: zeros)
  __shared__ __align__(16) bf16_t Plds[4][32][40]; // 10240 B

  const bf16_t* Qhb = Qh + (size_t)b * HWN * NINTER;
  const bf16_t* Khb = Kh + (size_t)b * HWN * NINTER;
  const bf16_t* Vb  = V + (size_t)b * NINTER * HWN;

  if (tid < 112) {
    int row = 128 + tid / 7;
    int c8 = (tid % 7) * 8;
    bf16x8 v;
#pragma unroll
    for (int j = 0; j < 8; j++) v[j] = (bf16_t)((row == 128) ? 1.0f : 0.0f);
    *(bf16x8*)(&Vlds[row][c8]) = v;
  }

  bf16x8 qf[2][4];
#pragma unroll
  for (int qs = 0; qs < 2; qs++) {
    const int qrow = qt * 128 + wv * 32 + qs * 16 + l15;
#pragma unroll
    for (int kc = 0; kc < 4; kc++)
      qf[qs][kc] = *(const bf16x8*)(Qhb + (size_t)qrow * NINTER + kc * 32 + quad * 8);
  }

  f32x4 o[2][8], ol[2];
#pragma unroll
  for (int qs = 0; qs < 2; qs++) {
#pragma unroll
    for (int dt = 0; dt < 8; dt++)
#pragma unroll
      for (int i = 0; i < 4; i++) o[qs][dt][i] = 0.f;
#pragma unroll
    for (int i = 0; i < 4; i++) ol[qs][i] = 0.f;
  }

  for (int t = 0; t < 32; t++) {
    __syncthreads();
#pragma unroll
    for (int i = 0; i < 2; i++) {          // K tile: 32 rows x 128 d
      int idx = tid + i * 256;
      int row = idx >> 4;
      int c8 = (idx & 15) * 8;
      *(uint4*)(&Klds[row][c8]) =
          *(const uint4*)(Khb + (size_t)(kbase + t * 32 + row) * NINTER + c8);
    }
#pragma unroll
    for (int i = 0; i < 2; i++) {          // V tile: 128 d x 32 m
      int idx = tid + i * 256;
      int row = idx >> 2;
      int c8 = (idx & 3) * 8;
      *(uint4*)(&Vlds[row][c8]) =
          *(const uint4*)(Vb + (size_t)row * HWN + kbase + t * 32 + c8);
    }
    __syncthreads();

    f32x4 s[2][2];
#pragma unroll
    for (int qs = 0; qs < 2; qs++)
#pragma unroll
      for (int ks = 0; ks < 2; ks++)
#pragma unroll
        for (int i = 0; i < 4; i++) s[qs][ks][i] = 0.f;
#pragma unroll
    for (int ks = 0; ks < 2; ks++)
#pragma unroll
      for (int kc = 0; kc < 4; kc++) {
        bf16x8 kf = *(const bf16x8*)(&Klds[ks * 16 + l15][kc * 32 + quad * 8]);
        s[0][ks] = __builtin_amdgcn_mfma_f32_16x16x32_bf16(qf[0][kc], kf, s[0][ks], 0, 0, 0);
        s[1][ks] = __builtin_amdgcn_mfma_f32_16x16x32_bf16(qf[1][kc], kf, s[1][ks], 0, 0, 0);
      }

#pragma unroll
    for (int qs = 0; qs < 2; qs++)
#pragma unroll
      for (int ks = 0; ks < 2; ks++)
#pragma unroll
        for (int r = 0; r < 4; r++)
          Plds[wv][qs * 16 + quad * 4 + r][ks * 16 + l15] =
              (bf16_t)fexp2(s[qs][ks][r] - SMAX);

    bf16x8 pf0 = *(const bf16x8*)(&Plds[wv][l15][quad * 8]);
    bf16x8 pf1 = *(const bf16x8*)(&Plds[wv][16 + l15][quad * 8]);
#pragma unroll
    for (int dt = 0; dt < 8; dt++) {
      bf16x8 vf = *(const bf16x8*)(&Vlds[dt * 16 + l15][quad * 8]);
      o[0][dt] = __builtin_amdgcn_mfma_f32_16x16x32_bf16(pf0, vf, o[0][dt], 0, 0, 0);
      o[1][dt] = __builtin_amdgcn_mfma_f32_16x16x32_bf16(pf1, vf, o[1][dt], 0, 0, 0);
    }
    bf16x8 vfl = *(const bf16x8*)(&Vlds[128 + l15][quad * 8]);
    ol[0] = __builtin_amdgcn_mfma_f32_16x16x32_bf16(pf0, vfl, ol[0], 0, 0, 0);
    ol[1] = __builtin_amdgcn_mfma_f32_16x16x32_bf16(pf1, vfl, ol[1], 0, 0, 0);
  }

  float* Ob = Opart + ((size_t)(b * NC + chunk) * HWN) * NINTER;
#pragma unroll
  for (int qs = 0; qs < 2; qs++)
#pragma unroll
    for (int r = 0; r < 4; r++) {
      int n = qt * 128 + wv * 32 + qs * 16 + quad * 4 + r;
#pragma unroll
      for (int dt = 0; dt < 8; dt++)
        Ob[(size_t)n * NINTER + dt * 16 + l15] = o[qs][dt][r];
      if (l15 == 0)
        Lp[(size_t)(b * NC + chunk) * HWN + n] = ol[qs][r];
    }
}

// Fused: combine OP chunks -> Y tile in LDS -> W conv -> WY bf16,
// + per-channel (sum, sumsq) atomics for BN stats.
__global__ __launch_bounds__(256, 4) void wconv_kernel(
    const float* __restrict__ ww, const float* __restrict__ Opart,
    const float* __restrict__ Lp, const float* __restrict__ Wb,
    bf16_t* __restrict__ WY, float* __restrict__ ST) {
  const int ntb = blockIdx.x;   // 128 tiles of 32 n
  const int b   = blockIdx.y;
  const int tid = threadIdx.x;
  const int lane = tid & 63;
  const int wv   = tid >> 6;
  const int l31  = lane & 31;
  const int half = lane >> 5;

  __shared__ __align__(16) bf16_t Ylds[32][136];
  __shared__ float Linv[32];

  // 1/l per row
  if (tid < 32) {
    int n = ntb * 32 + tid;
    float ls = 0.f;
#pragma unroll
    for (int c = 0; c < NC; c++) ls += Lp[(size_t)(b * NC + c) * HWN + n];
    Linv[tid] = 1.f / ls;
  }

  // sum the 4 OP chunks: thread -> (row = tid>>3, 16-d group = tid&7)
  const int nrow = tid >> 3;
  const int dgrp = tid & 7;
  float oacc[16];
#pragma unroll
  for (int j = 0; j < 16; j++) oacc[j] = 0.f;
#pragma unroll
  for (int c = 0; c < NC; c++) {
    const float* Op = Opart +
        ((size_t)(b * NC + c) * HWN + ntb * 32 + nrow) * NINTER + dgrp * 16;
#pragma unroll
    for (int q = 0; q < 4; q++) {
      f32x4 v = *(const f32x4*)(Op + q * 4);
#pragma unroll
      for (int j = 0; j < 4; j++) oacc[q * 4 + j] += v[j];
    }
  }
  __syncthreads();   // Linv ready
  {
    float inv = Linv[nrow];
    bf16x8 y0, y1;
#pragma unroll
    for (int j = 0; j < 8; j++) {
      y0[j] = (bf16_t)(oacc[j] * inv);
      y1[j] = (bf16_t)(oacc[8 + j] * inv);
    }
    *(bf16x8*)(&Ylds[nrow][dgrp * 16]) = y0;
    *(bf16x8*)(&Ylds[nrow][dgrp * 16 + 8]) = y1;
  }
  __syncthreads();

  // W conv from LDS Y tile; W read fp32 + converted in-register
  f32x16 acc[2];
#pragma unroll
  for (int c = 0; c < 2; c++)
#pragma unroll
    for (int i = 0; i < 16; i++) acc[c][i] = 0.f;

#pragma unroll
  for (int k0 = 0; k0 < 128; k0 += 16) {
    bf16x8 a0 = load_cvt8(ww + (size_t)(wv * 64 + l31) * NINTER + k0 + half * 8);
    bf16x8 a1 = load_cvt8(ww + (size_t)(wv * 64 + 32 + l31) * NINTER + k0 + half * 8);
    bf16x8 b0 = *(const bf16x8*)(&Ylds[l31][k0 + half * 8]);
    acc[0] = __builtin_amdgcn_mfma_f32_32x32x16_bf16(a0, b0, acc[0], 0, 0, 0);
    acc[1] = __builtin_amdgcn_mfma_f32_32x32x16_bf16(a1, b0, acc[1], 0, 0, 0);
  }

  // epilogue: WY store + per-channel stats reduction (32 n per block)
  bf16_t* dst = WY + (size_t)b * 256 * HWN + ntb * 32;
#pragma unroll
  for (int ct = 0; ct < 2; ct++)
#pragma unroll
    for (int r = 0; r < 16; r++) {
      int co = wv * 64 + ct * 32 + (r & 3) + 8 * (r >> 2) + 4 * half;
      float v = acc[ct][r] + Wb[co];
      dst[(size_t)co * HWN + l31] = (bf16_t)v;
      float s = v, s2 = v * v;
#pragma unroll
      for (int off = 1; off < 32; off <<= 1) {   // stays within half-wave
        s += __shfl_xor(s, off);
        s2 += __shfl_xor(s2, off);
      }
      if (l31 == 0) {
        atomicAdd(&ST[co], s);
        atomicAdd(&ST[256 + co], s2);
      }
    }
}

// BN apply + residual; mean/rstd computed inline from accumulated sums.
__global__ __launch_bounds__(256) void bn_kernel(
    const bf16_t* __restrict__ WY, const float* __restrict__ x,
    const float* __restrict__ ST, const float* __restrict__ gamma,
    const float* __restrict__ beta, float* __restrict__ out) {
  int idx = blockIdx.x * 256 + threadIdx.x;
  int e = idx * 4;
  int c = (e >> 12) & 255;
  bf16x4 w4 = *(const bf16x4*)(WY + e);
  float4 xv = *(const float4*)(x + e);
  float S = ST[c], S2 = ST[256 + c];
  float mean = S * (1.f / 16384.f);
  float var = S2 * (1.f / 16384.f) - mean * mean;
  float g = gamma[c] * rsqrtf(var + BN_EPS);
  float bb = beta[c];
  float4 o;
  o.x = g * ((float)w4[0] - mean) + bb + xv.x;
  o.y = g * ((float)w4[1] - mean) + bb + xv.y;
  o.z = g * ((float)w4[2] - mean) + bb + xv.z;
  o.w = g * ((float)w4[3] - mean) + bb + xv.w;
  *(float4*)(out + e) = o;
}

extern "C" void kernel_launch(void* const* d_in, const int* in_sizes, int n_in,
                              void* d_out, int out_size, void* d_ws, size_t ws_size,
                              hipStream_t stream) {
  const float* x       = (const float*)d_in[0];
  const float* theta_w = (const float*)d_in[1];
  const float* theta_b = (const float*)d_in[2];
  const float* phi_w   = (const float*)d_in[3];
  const float* phi_b   = (const float*)d_in[4];
  const float* g_w     = (const float*)d_in[5];
  const float* g_b     = (const float*)d_in[6];
  const float* W_w     = (const float*)d_in[7];
  const float* W_b     = (const float*)d_in[8];
  const float* bn_g    = (const float*)d_in[9];
  const float* bn_b    = (const float*)d_in[10];
  float* out = (float*)d_out;

  char* ws = (char*)d_ws;
  bf16_t* Qh  = (bf16_t*)(ws + OFF_QH);
  bf16_t* Kh  = (bf16_t*)(ws + OFF_KH);
  bf16_t* V   = (bf16_t*)(ws + OFF_V);
  float*  OP  = (float*)(ws + OFF_OP);
  bf16_t* WY  = (bf16_t*)(ws + OFF_WY);
  float*  LP  = (float*)(ws + OFF_LP);
  float*  ST  = (float*)(ws + OFF_ST);

  qkv_kernel<<<dim3(128, NBATCH), 256, 0, stream>>>(
      x, theta_w, phi_w, g_w, theta_b, phi_b, g_b, Qh, Kh, V, ST);
  attn_kernel<<<dim3(32, NC, NBATCH), 256, 0, stream>>>(
      Qh, Kh, V, OP, LP);
  wconv_kernel<<<dim3(128, NBATCH), 256, 0, stream>>>(
      W_w, OP, LP, W_b, WY, ST);
  bn_kernel<<<4096, 256, 0, stream>>>(WY, x, ST, bn_g, bn_b, out);
}

// Round 11
// 183.175 us; speedup vs baseline: 1.7950x; 1.7950x over previous
//
#include <hip/hip_runtime.h>
#include <hip/hip_bf16.h>

#define HWN   4096
#define CIN   256
#define NINTER 128
#define NBATCH 4
#define BN_EPS 1e-5f
#define NC    4          // key chunks for attention pass 1
#define CHUNK 1024       // keys per chunk
#define LOG2E 1.4426950408889634f
#define SMAX  64.0f      // fixed softmax max (base-2 units; row max ~55 worst-case)

typedef __bf16 bf16_t;
typedef __bf16 bf16x8 __attribute__((ext_vector_type(8)));
typedef __bf16 bf16x4 __attribute__((ext_vector_type(4)));
typedef float  f32x4  __attribute__((ext_vector_type(4)));
typedef float  f32x16 __attribute__((ext_vector_type(16)));

__device__ __forceinline__ float fexp2(float x) {
  return __builtin_amdgcn_exp2f(x);
}

__device__ __forceinline__ void split_bf16(float v, bf16_t& h, bf16_t& l) {
  h = (bf16_t)v;
  l = (bf16_t)(v - (float)h);
}

// Workspace (bytes): QH 4M, KH 4M, V 4M, OP fp32 32M, WY bf16 8M (disjoint
// from OP: wconv reads OP and writes WY in the same kernel), LP 256K,
// WBF 512K, ST 2K. Total ~59.5 MB.
#define OFF_QH  0
#define OFF_KH  4194304
#define OFF_V   8388608
#define OFF_OP  12582912   // 32 MiB fp32 partials
#define OFF_WY  46137344   // 8 MiB bf16
#define OFF_LP  54525952
#define OFF_WBF 54790144
#define OFF_ST  55314432

__global__ __launch_bounds__(256) void convert_weights(
    const float* __restrict__ tw, const float* __restrict__ pw,
    const float* __restrict__ gw, const float* __restrict__ ww,
    bf16_t* __restrict__ out) {
  int i = blockIdx.x * 256 + threadIdx.x;  // 131072 total
  float v;
  if (i < 32768)        v = tw[i];
  else if (i < 65536)   v = pw[i - 32768];
  else if (i < 98304)   v = gw[i - 65536];
  else                  v = ww[i - 98304];
  bf16_t h, l;
  split_bf16(v, h, l);
  out[i] = h;
  out[131072 + i] = l;
}

// Fused QKV conv (R9-identical). n-tile 32, grid (128, 4).
__global__ __launch_bounds__(256, 4) void qkv_kernel(
    const float* __restrict__ x, const bf16_t* __restrict__ wbf,
    const float* __restrict__ tb, const float* __restrict__ pb,
    const float* __restrict__ gb,
    bf16_t* __restrict__ Qh, bf16_t* __restrict__ Kh, bf16_t* __restrict__ V) {
  const int ntb  = blockIdx.x;   // 128 tiles of 32 n
  const int b    = blockIdx.y;
  const int tid  = threadIdx.x;
  const int lane = tid & 63;
  const int wv   = tid >> 6;
  const int l31  = lane & 31;
  const int half = lane >> 5;

  __shared__ __align__(16) bf16_t smem[4608];            // 9216 B
  bf16_t (*xTh)[72] = (bf16_t(*)[72])smem;               // [32][72]
  bf16_t (*xTl)[72] = (bf16_t(*)[72])(smem + 2304);      // [32][72]
  bf16_t (*Tr)[136] = (bf16_t(*)[136])smem;              // [32][136] (reuse)

  const bf16_t* Th = wbf;                  // theta hi [128][256]
  const bf16_t* Tl = wbf + 131072;         // theta lo
  const bf16_t* Ph = wbf + 32768;          // phi hi
  const bf16_t* Pl = wbf + 131072 + 32768; // phi lo
  const bf16_t* Gh = wbf + 65536;          // g hi
  const float*  xb = x + (size_t)b * CIN * HWN + ntb * 32;

  f32x16 aq, ak, av;
#pragma unroll
  for (int i = 0; i < 16; i++) { aq[i] = 0.f; ak[i] = 0.f; av[i] = 0.f; }

  for (int c0 = 0; c0 < 256; c0 += 64) {
    __syncthreads();
#pragma unroll
    for (int i = 0; i < 8; i++) {         // 2048 elements: 64c x 32n
      int idx = tid + i * 256;
      int cc = idx >> 5;
      int nn = idx & 31;
      float v = xb[(size_t)(c0 + cc) * HWN + nn];
      bf16_t h, l;
      split_bf16(v, h, l);
      xTh[nn][cc] = h;
      xTl[nn][cc] = l;
    }
    __syncthreads();
#pragma unroll
    for (int kk = 0; kk < 64; kk += 16) {
      size_t woff = (size_t)(32 * wv + l31) * 256 + c0 + kk + half * 8;
      bf16x8 th = *(const bf16x8*)(Th + woff);
      bf16x8 tl = *(const bf16x8*)(Tl + woff);
      bf16x8 ph = *(const bf16x8*)(Ph + woff);
      bf16x8 pl = *(const bf16x8*)(Pl + woff);
      bf16x8 gh = *(const bf16x8*)(Gh + woff);
      bf16x8 bh = *(const bf16x8*)(&xTh[l31][kk + half * 8]);
      bf16x8 bl = *(const bf16x8*)(&xTl[l31][kk + half * 8]);
      aq = __builtin_amdgcn_mfma_f32_32x32x16_bf16(th, bh, aq, 0, 0, 0);
      aq = __builtin_amdgcn_mfma_f32_32x32x16_bf16(th, bl, aq, 0, 0, 0);
      aq = __builtin_amdgcn_mfma_f32_32x32x16_bf16(tl, bh, aq, 0, 0, 0);
      ak = __builtin_amdgcn_mfma_f32_32x32x16_bf16(ph, bh, ak, 0, 0, 0);
      ak = __builtin_amdgcn_mfma_f32_32x32x16_bf16(ph, bl, ak, 0, 0, 0);
      ak = __builtin_amdgcn_mfma_f32_32x32x16_bf16(pl, bh, ak, 0, 0, 0);
      av = __builtin_amdgcn_mfma_f32_32x32x16_bf16(gh, bh, av, 0, 0, 0);
    }
  }

  // ---- epilogue: 2 LDS-transpose rounds (Qh, Kh) + direct V store ----
  const int trow = tid >> 3;          // 0..31
  const int tc16 = (tid & 7) * 16;    // 0..112
  bf16_t* qh = Qh + ((size_t)b * HWN + ntb * 32) * NINTER;
  bf16_t* kh = Kh + ((size_t)b * HWN + ntb * 32) * NINTER;

#pragma unroll
  for (int rnd = 0; rnd < 2; rnd++) {
    __syncthreads();
#pragma unroll
    for (int rg = 0; rg < 4; rg++) {
      int och0 = 32 * wv + 8 * rg + 4 * half;
#pragma unroll
      for (int j = 0; j < 4; j++) {
        float v = (rnd == 0) ? (aq[rg * 4 + j] + tb[och0 + j]) * LOG2E
                             : (ak[rg * 4 + j] + pb[och0 + j]);
        Tr[l31][och0 + j] = (bf16_t)v;
      }
    }
    __syncthreads();
    bf16_t* dst = (rnd == 0) ? qh : kh;
    bf16x8 v0 = *(const bf16x8*)(&Tr[trow][tc16]);
    bf16x8 v1 = *(const bf16x8*)(&Tr[trow][tc16 + 8]);
    *(bf16x8*)(dst + (size_t)trow * NINTER + tc16) = v0;
    *(bf16x8*)(dst + (size_t)trow * NINTER + tc16 + 8) = v1;
  }

  const int n = ntb * 32 + l31;
  bf16_t* vd = V + (size_t)b * NINTER * HWN;
#pragma unroll
  for (int r = 0; r < 16; r++) {
    int och = 32 * wv + (r & 3) + 8 * (r >> 2) + 4 * half;
    vd[(size_t)och * HWN + n] = (bf16_t)(av[r] + gb[och]);
  }
}

// Flash attention pass 1 (R9-identical): fixed-max softmax, single-Q.
// Block = 128 q rows (4 waves x 32 q), 32 K-tiles of 32 keys.
// grid (32 qt, 4 chunk, 4 b) = 512 blocks = 2/CU.
__global__ __launch_bounds__(256, 2) void attn_kernel(
    const bf16_t* __restrict__ Qh, const bf16_t* __restrict__ Kh,
    const bf16_t* __restrict__ V,
    float* __restrict__ Opart, float* __restrict__ Lp) {
  const int qt    = blockIdx.x;
  const int chunk = blockIdx.y;
  const int b     = blockIdx.z;
  const int tid   = threadIdx.x;
  const int lane  = tid & 63;
  const int wv    = tid >> 6;
  const int l15   = lane & 15;
  const int quad  = lane >> 4;
  const int kbase = chunk * CHUNK;

  __shared__ __align__(16) bf16_t Klds[32][136];   // 8704 B
  __shared__ __align__(16) bf16_t Vlds[144][56];   // 16128 B (row 128: ones; 129+: zeros)
  __shared__ __align__(16) bf16_t Plds[4][32][40]; // 10240 B

  const bf16_t* Qhb = Qh + (size_t)b * HWN * NINTER;
  const bf16_t* Khb = Kh + (size_t)b * HWN * NINTER;
  const bf16_t* Vb  = V + (size_t)b * NINTER * HWN;

  if (tid < 112) {
    int row = 128 + tid / 7;
    int c8 = (tid % 7) * 8;
    bf16x8 v;
#pragma unroll
    for (int j = 0; j < 8; j++) v[j] = (bf16_t)((row == 128) ? 1.0f : 0.0f);
    *(bf16x8*)(&Vlds[row][c8]) = v;
  }

  bf16x8 qf[2][4];
#pragma unroll
  for (int qs = 0; qs < 2; qs++) {
    const int qrow = qt * 128 + wv * 32 + qs * 16 + l15;
#pragma unroll
    for (int kc = 0; kc < 4; kc++)
      qf[qs][kc] = *(const bf16x8*)(Qhb + (size_t)qrow * NINTER + kc * 32 + quad * 8);
  }

  f32x4 o[2][8], ol[2];
#pragma unroll
  for (int qs = 0; qs < 2; qs++) {
#pragma unroll
    for (int dt = 0; dt < 8; dt++)
#pragma unroll
      for (int i = 0; i < 4; i++) o[qs][dt][i] = 0.f;
#pragma unroll
    for (int i = 0; i < 4; i++) ol[qs][i] = 0.f;
  }

  for (int t = 0; t < 32; t++) {
    __syncthreads();
#pragma unroll
    for (int i = 0; i < 2; i++) {          // K tile: 32 rows x 128 d
      int idx = tid + i * 256;
      int row = idx >> 4;
      int c8 = (idx & 15) * 8;
      *(uint4*)(&Klds[row][c8]) =
          *(const uint4*)(Khb + (size_t)(kbase + t * 32 + row) * NINTER + c8);
    }
#pragma unroll
    for (int i = 0; i < 2; i++) {          // V tile: 128 d x 32 m
      int idx = tid + i * 256;
      int row = idx >> 2;
      int c8 = (idx & 3) * 8;
      *(uint4*)(&Vlds[row][c8]) =
          *(const uint4*)(Vb + (size_t)row * HWN + kbase + t * 32 + c8);
    }
    __syncthreads();

    f32x4 s[2][2];
#pragma unroll
    for (int qs = 0; qs < 2; qs++)
#pragma unroll
      for (int ks = 0; ks < 2; ks++)
#pragma unroll
        for (int i = 0; i < 4; i++) s[qs][ks][i] = 0.f;
#pragma unroll
    for (int ks = 0; ks < 2; ks++)
#pragma unroll
      for (int kc = 0; kc < 4; kc++) {
        bf16x8 kf = *(const bf16x8*)(&Klds[ks * 16 + l15][kc * 32 + quad * 8]);
        s[0][ks] = __builtin_amdgcn_mfma_f32_16x16x32_bf16(qf[0][kc], kf, s[0][ks], 0, 0, 0);
        s[1][ks] = __builtin_amdgcn_mfma_f32_16x16x32_bf16(qf[1][kc], kf, s[1][ks], 0, 0, 0);
      }

#pragma unroll
    for (int qs = 0; qs < 2; qs++)
#pragma unroll
      for (int ks = 0; ks < 2; ks++)
#pragma unroll
        for (int r = 0; r < 4; r++)
          Plds[wv][qs * 16 + quad * 4 + r][ks * 16 + l15] =
              (bf16_t)fexp2(s[qs][ks][r] - SMAX);

    bf16x8 pf0 = *(const bf16x8*)(&Plds[wv][l15][quad * 8]);
    bf16x8 pf1 = *(const bf16x8*)(&Plds[wv][16 + l15][quad * 8]);
#pragma unroll
    for (int dt = 0; dt < 8; dt++) {
      bf16x8 vf = *(const bf16x8*)(&Vlds[dt * 16 + l15][quad * 8]);
      o[0][dt] = __builtin_amdgcn_mfma_f32_16x16x32_bf16(pf0, vf, o[0][dt], 0, 0, 0);
      o[1][dt] = __builtin_amdgcn_mfma_f32_16x16x32_bf16(pf1, vf, o[1][dt], 0, 0, 0);
    }
    bf16x8 vfl = *(const bf16x8*)(&Vlds[128 + l15][quad * 8]);
    ol[0] = __builtin_amdgcn_mfma_f32_16x16x32_bf16(pf0, vfl, ol[0], 0, 0, 0);
    ol[1] = __builtin_amdgcn_mfma_f32_16x16x32_bf16(pf1, vfl, ol[1], 0, 0, 0);
  }

  float* Ob = Opart + ((size_t)(b * NC + chunk) * HWN) * NINTER;
#pragma unroll
  for (int qs = 0; qs < 2; qs++)
#pragma unroll
    for (int r = 0; r < 4; r++) {
      int n = qt * 128 + wv * 32 + qs * 16 + quad * 4 + r;
#pragma unroll
      for (int dt = 0; dt < 8; dt++)
        Ob[(size_t)n * NINTER + dt * 16 + l15] = o[qs][dt][r];
      if (l15 == 0)
        Lp[(size_t)(b * NC + chunk) * HWN + n] = ol[qs][r];
    }
}

// Fused combine + W conv: sum OP chunks -> normalize -> Y tile in LDS ->
// MFMA -> WY bf16. NO stats atomics (R10 lesson). n-tile 32, grid (128,4).
__global__ __launch_bounds__(256, 4) void wconv_kernel(
    const bf16_t* __restrict__ Wbf, const float* __restrict__ Opart,
    const float* __restrict__ Lp, const float* __restrict__ Wb,
    bf16_t* __restrict__ WY) {
  const int ntb = blockIdx.x;   // 128 tiles of 32 n
  const int b   = blockIdx.y;
  const int tid = threadIdx.x;
  const int lane = tid & 63;
  const int wv   = tid >> 6;
  const int l31  = lane & 31;
  const int half = lane >> 5;

  __shared__ __align__(16) bf16_t Ylds[32][136];
  __shared__ float Linv[32];

  if (tid < 32) {
    int n = ntb * 32 + tid;
    float ls = 0.f;
#pragma unroll
    for (int c = 0; c < NC; c++) ls += Lp[(size_t)(b * NC + c) * HWN + n];
    Linv[tid] = 1.f / ls;
  }

  // sum the NC OP chunks: thread -> (row = tid>>3, 16-d group = tid&7)
  const int nrow = tid >> 3;
  const int dgrp = tid & 7;
  float oacc[16];
#pragma unroll
  for (int j = 0; j < 16; j++) oacc[j] = 0.f;
#pragma unroll
  for (int c = 0; c < NC; c++) {
    const float* Op = Opart +
        ((size_t)(b * NC + c) * HWN + ntb * 32 + nrow) * NINTER + dgrp * 16;
#pragma unroll
    for (int q = 0; q < 4; q++) {
      f32x4 v = *(const f32x4*)(Op + q * 4);
#pragma unroll
      for (int j = 0; j < 4; j++) oacc[q * 4 + j] += v[j];
    }
  }
  __syncthreads();   // Linv ready
  {
    float inv = Linv[nrow];
    bf16x8 y0, y1;
#pragma unroll
    for (int j = 0; j < 8; j++) {
      y0[j] = (bf16_t)(oacc[j] * inv);
      y1[j] = (bf16_t)(oacc[8 + j] * inv);
    }
    *(bf16x8*)(&Ylds[nrow][dgrp * 16]) = y0;
    *(bf16x8*)(&Ylds[nrow][dgrp * 16 + 8]) = y1;
  }
  __syncthreads();

  const bf16_t* Wh = Wbf + 98304;  // [256][128] hi
  f32x16 acc[2];
#pragma unroll
  for (int c = 0; c < 2; c++)
#pragma unroll
    for (int i = 0; i < 16; i++) acc[c][i] = 0.f;

#pragma unroll
  for (int k0 = 0; k0 < 128; k0 += 16) {
    bf16x8 a0 = *(const bf16x8*)(Wh + (size_t)(wv * 64 + l31) * NINTER + k0 + half * 8);
    bf16x8 a1 = *(const bf16x8*)(Wh + (size_t)(wv * 64 + 32 + l31) * NINTER + k0 + half * 8);
    bf16x8 b0 = *(const bf16x8*)(&Ylds[l31][k0 + half * 8]);
    acc[0] = __builtin_amdgcn_mfma_f32_32x32x16_bf16(a0, b0, acc[0], 0, 0, 0);
    acc[1] = __builtin_amdgcn_mfma_f32_32x32x16_bf16(a1, b0, acc[1], 0, 0, 0);
  }

  bf16_t* dst = WY + (size_t)b * 256 * HWN + ntb * 32;
#pragma unroll
  for (int ct = 0; ct < 2; ct++)
#pragma unroll
    for (int r = 0; r < 16; r++) {
      int co = wv * 64 + ct * 32 + (r & 3) + 8 * (r >> 2) + 4 * half;
      dst[(size_t)co * HWN + l31] = (bf16_t)(acc[ct][r] + Wb[co]);
    }
}

__global__ __launch_bounds__(256) void stats_kernel(
    const bf16_t* __restrict__ WY, float* __restrict__ stats) {
  const int c = blockIdx.x;
  const int tid = threadIdx.x;
  float s = 0.f, s2 = 0.f;
  for (int b = 0; b < NBATCH; b++) {
    const bf16_t* p = WY + ((size_t)b * 256 + c) * HWN;
    for (int i = tid * 8; i < HWN; i += 2048) {
      bf16x8 v8 = *(const bf16x8*)(p + i);
#pragma unroll
      for (int j = 0; j < 8; j++) {
        float v = (float)v8[j];
        s += v;
        s2 += v * v;
      }
    }
  }
#pragma unroll
  for (int off = 1; off < 64; off <<= 1) {
    s += __shfl_xor(s, off);
    s2 += __shfl_xor(s2, off);
  }
  __shared__ float red[8];
  int wv = tid >> 6;
  if ((tid & 63) == 0) { red[wv] = s; red[4 + wv] = s2; }
  __syncthreads();
  if (tid == 0) {
    float S = red[0] + red[1] + red[2] + red[3];
    float S2 = red[4] + red[5] + red[6] + red[7];
    float mean = S * (1.f / 16384.f);
    float var = S2 * (1.f / 16384.f) - mean * mean;
    stats[c] = mean;
    stats[256 + c] = rsqrtf(var + BN_EPS);
  }
}

__global__ __launch_bounds__(256) void bn_kernel(
    const bf16_t* __restrict__ WY, const float* __restrict__ x,
    const float* __restrict__ stats, const float* __restrict__ gamma,
    const float* __restrict__ beta, float* __restrict__ out) {
  int idx = blockIdx.x * 256 + threadIdx.x;
  int e = idx * 4;
  int c = (e >> 12) & 255;
  bf16x4 w4 = *(const bf16x4*)(WY + e);
  float4 xv = *(const float4*)(x + e);
  float mean = stats[c];
  float g = gamma[c] * stats[256 + c];
  float bb = beta[c];
  float4 o;
  o.x = g * ((float)w4[0] - mean) + bb + xv.x;
  o.y = g * ((float)w4[1] - mean) + bb + xv.y;
  o.z = g * ((float)w4[2] - mean) + bb + xv.z;
  o.w = g * ((float)w4[3] - mean) + bb + xv.w;
  *(float4*)(out + e) = o;
}

extern "C" void kernel_launch(void* const* d_in, const int* in_sizes, int n_in,
                              void* d_out, int out_size, void* d_ws, size_t ws_size,
                              hipStream_t stream) {
  const float* x       = (const float*)d_in[0];
  const float* theta_b = (const float*)d_in[2];
  const float* phi_b   = (const float*)d_in[4];
  const float* g_b     = (const float*)d_in[6];
  const float* W_b     = (const float*)d_in[8];
  const float* bn_g    = (const float*)d_in[9];
  const float* bn_b    = (const float*)d_in[10];
  float* out = (float*)d_out;

  char* ws = (char*)d_ws;
  bf16_t* Qh  = (bf16_t*)(ws + OFF_QH);
  bf16_t* Kh  = (bf16_t*)(ws + OFF_KH);
  bf16_t* V   = (bf16_t*)(ws + OFF_V);
  float*  OP  = (float*)(ws + OFF_OP);
  bf16_t* WY  = (bf16_t*)(ws + OFF_WY);
  float*  LP  = (float*)(ws + OFF_LP);
  bf16_t* WBF = (bf16_t*)(ws + OFF_WBF);
  float*  ST  = (float*)(ws + OFF_ST);

  convert_weights<<<512, 256, 0, stream>>>(
      (const float*)d_in[1], (const float*)d_in[3],
      (const float*)d_in[5], (const float*)d_in[7], WBF);
  qkv_kernel<<<dim3(128, NBATCH), 256, 0, stream>>>(
      x, WBF, theta_b, phi_b, g_b, Qh, Kh, V);
  attn_kernel<<<dim3(32, NC, NBATCH), 256, 0, stream>>>(
      Qh, Kh, V, OP, LP);
  wconv_kernel<<<dim3(128, NBATCH), 256, 0, stream>>>(
      WBF, OP, LP, W_b, WY);
  stats_kernel<<<256, 256, 0, stream>>>(WY, ST);
  bn_kernel<<<4096, 256, 0, stream>>>(WY, x, ST, bn_g, bn_b, out);
}

// Round 12
// 181.336 us; speedup vs baseline: 1.8132x; 1.0101x over previous
//
#include <hip/hip_runtime.h>
#include <hip/hip_bf16.h>

#define HWN   4096
#define CIN   256
#define NINTER 128
#define NBATCH 4
#define BN_EPS 1e-5f
#define NC    4          // key chunks for attention pass 1
#define CHUNK 1024       // keys per chunk
#define LOG2E 1.4426950408889634f
#define SMAX  64.0f      // fixed softmax max (base-2 units; row max ~55 worst-case)

typedef __bf16 bf16_t;
typedef __bf16 bf16x8 __attribute__((ext_vector_type(8)));
typedef __bf16 bf16x4 __attribute__((ext_vector_type(4)));
typedef float  f32x4  __attribute__((ext_vector_type(4)));
typedef float  f32x16 __attribute__((ext_vector_type(16)));

__device__ __forceinline__ float fexp2(float x) {
  return __builtin_amdgcn_exp2f(x);
}

__device__ __forceinline__ void split_bf16(float v, bf16_t& h, bf16_t& l) {
  h = (bf16_t)v;
  l = (bf16_t)(v - (float)h);
}

// Workspace (bytes): QH 4M, KH 4M, V 4M, OP fp32 32M, WY bf16 8M (disjoint
// from OP: wconv reads OP and writes WY in the same kernel), LP 256K,
// WBF 512K, ST 2K. Total ~59.5 MB.
#define OFF_QH  0
#define OFF_KH  4194304
#define OFF_V   8388608
#define OFF_OP  12582912   // 32 MiB fp32 partials
#define OFF_WY  46137344   // 8 MiB bf16
#define OFF_LP  54525952
#define OFF_WBF 54790144
#define OFF_ST  55314432

__global__ __launch_bounds__(256) void convert_weights(
    const float* __restrict__ tw, const float* __restrict__ pw,
    const float* __restrict__ gw, const float* __restrict__ ww,
    bf16_t* __restrict__ out) {
  int i = blockIdx.x * 256 + threadIdx.x;  // 131072 total
  float v;
  if (i < 32768)        v = tw[i];
  else if (i < 65536)   v = pw[i - 32768];
  else if (i < 98304)   v = gw[i - 65536];
  else                  v = ww[i - 98304];
  bf16_t h, l;
  split_bf16(v, h, l);
  out[i] = h;
  out[131072 + i] = l;
}

// Fused QKV conv (R9-identical). n-tile 32, grid (128, 4).
__global__ __launch_bounds__(256, 4) void qkv_kernel(
    const float* __restrict__ x, const bf16_t* __restrict__ wbf,
    const float* __restrict__ tb, const float* __restrict__ pb,
    const float* __restrict__ gb,
    bf16_t* __restrict__ Qh, bf16_t* __restrict__ Kh, bf16_t* __restrict__ V) {
  const int ntb  = blockIdx.x;   // 128 tiles of 32 n
  const int b    = blockIdx.y;
  const int tid  = threadIdx.x;
  const int lane = tid & 63;
  const int wv   = tid >> 6;
  const int l31  = lane & 31;
  const int half = lane >> 5;

  __shared__ __align__(16) bf16_t smem[4608];            // 9216 B
  bf16_t (*xTh)[72] = (bf16_t(*)[72])smem;               // [32][72]
  bf16_t (*xTl)[72] = (bf16_t(*)[72])(smem + 2304);      // [32][72]
  bf16_t (*Tr)[136] = (bf16_t(*)[136])smem;              // [32][136] (reuse)

  const bf16_t* Th = wbf;                  // theta hi [128][256]
  const bf16_t* Tl = wbf + 131072;         // theta lo
  const bf16_t* Ph = wbf + 32768;          // phi hi
  const bf16_t* Pl = wbf + 131072 + 32768; // phi lo
  const bf16_t* Gh = wbf + 65536;          // g hi
  const float*  xb = x + (size_t)b * CIN * HWN + ntb * 32;

  f32x16 aq, ak, av;
#pragma unroll
  for (int i = 0; i < 16; i++) { aq[i] = 0.f; ak[i] = 0.f; av[i] = 0.f; }

  for (int c0 = 0; c0 < 256; c0 += 64) {
    __syncthreads();
#pragma unroll
    for (int i = 0; i < 8; i++) {         // 2048 elements: 64c x 32n
      int idx = tid + i * 256;
      int cc = idx >> 5;
      int nn = idx & 31;
      float v = xb[(size_t)(c0 + cc) * HWN + nn];
      bf16_t h, l;
      split_bf16(v, h, l);
      xTh[nn][cc] = h;
      xTl[nn][cc] = l;
    }
    __syncthreads();
#pragma unroll
    for (int kk = 0; kk < 64; kk += 16) {
      size_t woff = (size_t)(32 * wv + l31) * 256 + c0 + kk + half * 8;
      bf16x8 th = *(const bf16x8*)(Th + woff);
      bf16x8 tl = *(const bf16x8*)(Tl + woff);
      bf16x8 ph = *(const bf16x8*)(Ph + woff);
      bf16x8 pl = *(const bf16x8*)(Pl + woff);
      bf16x8 gh = *(const bf16x8*)(Gh + woff);
      bf16x8 bh = *(const bf16x8*)(&xTh[l31][kk + half * 8]);
      bf16x8 bl = *(const bf16x8*)(&xTl[l31][kk + half * 8]);
      aq = __builtin_amdgcn_mfma_f32_32x32x16_bf16(th, bh, aq, 0, 0, 0);
      aq = __builtin_amdgcn_mfma_f32_32x32x16_bf16(th, bl, aq, 0, 0, 0);
      aq = __builtin_amdgcn_mfma_f32_32x32x16_bf16(tl, bh, aq, 0, 0, 0);
      ak = __builtin_amdgcn_mfma_f32_32x32x16_bf16(ph, bh, ak, 0, 0, 0);
      ak = __builtin_amdgcn_mfma_f32_32x32x16_bf16(ph, bl, ak, 0, 0, 0);
      ak = __builtin_amdgcn_mfma_f32_32x32x16_bf16(pl, bh, ak, 0, 0, 0);
      av = __builtin_amdgcn_mfma_f32_32x32x16_bf16(gh, bh, av, 0, 0, 0);
    }
  }

  // ---- epilogue: 2 LDS-transpose rounds (Qh, Kh) + direct V store ----
  const int trow = tid >> 3;          // 0..31
  const int tc16 = (tid & 7) * 16;    // 0..112
  bf16_t* qh = Qh + ((size_t)b * HWN + ntb * 32) * NINTER;
  bf16_t* kh = Kh + ((size_t)b * HWN + ntb * 32) * NINTER;

#pragma unroll
  for (int rnd = 0; rnd < 2; rnd++) {
    __syncthreads();
#pragma unroll
    for (int rg = 0; rg < 4; rg++) {
      int och0 = 32 * wv + 8 * rg + 4 * half;
#pragma unroll
      for (int j = 0; j < 4; j++) {
        float v = (rnd == 0) ? (aq[rg * 4 + j] + tb[och0 + j]) * LOG2E
                             : (ak[rg * 4 + j] + pb[och0 + j]);
        Tr[l31][och0 + j] = (bf16_t)v;
      }
    }
    __syncthreads();
    bf16_t* dst = (rnd == 0) ? qh : kh;
    bf16x8 v0 = *(const bf16x8*)(&Tr[trow][tc16]);
    bf16x8 v1 = *(const bf16x8*)(&Tr[trow][tc16 + 8]);
    *(bf16x8*)(dst + (size_t)trow * NINTER + tc16) = v0;
    *(bf16x8*)(dst + (size_t)trow * NINTER + tc16 + 8) = v1;
  }

  const int n = ntb * 32 + l31;
  bf16_t* vd = V + (size_t)b * NINTER * HWN;
#pragma unroll
  for (int r = 0; r < 16; r++) {
    int och = 32 * wv + (r & 3) + 8 * (r >> 2) + 4 * half;
    vd[(size_t)och * HWN + n] = (bf16_t)(av[r] + gb[och]);
  }
}

// Flash attention pass 1: fixed-max softmax, single-Q, S computed
// TRANSPOSED (A=kf, B=qf) so P-writes are contiguous bf16x4 per lane
// (4x ds_write_b64 vs 16x conflicted ds_write_b16 — the R9/R11 LDS hotspot).
// Block = 128 q rows (4 waves x 32 q), 32 K-tiles of 32 keys.
// grid (32 qt, 4 chunk, 4 b) = 512 blocks = 2/CU.
__global__ __launch_bounds__(256, 2) void attn_kernel(
    const bf16_t* __restrict__ Qh, const bf16_t* __restrict__ Kh,
    const bf16_t* __restrict__ V,
    float* __restrict__ Opart, float* __restrict__ Lp) {
  const int qt    = blockIdx.x;
  const int chunk = blockIdx.y;
  const int b     = blockIdx.z;
  const int tid   = threadIdx.x;
  const int lane  = tid & 63;
  const int wv    = tid >> 6;
  const int l15   = lane & 15;
  const int quad  = lane >> 4;
  const int kbase = chunk * CHUNK;

  __shared__ __align__(16) bf16_t Klds[32][136];   // 8704 B
  __shared__ __align__(16) bf16_t Vlds[144][56];   // 16128 B (row 128: ones; 129+: zeros)
  __shared__ __align__(16) bf16_t Plds[4][32][40]; // 10240 B, [wave][q][key]

  const bf16_t* Qhb = Qh + (size_t)b * HWN * NINTER;
  const bf16_t* Khb = Kh + (size_t)b * HWN * NINTER;
  const bf16_t* Vb  = V + (size_t)b * NINTER * HWN;

  if (tid < 112) {
    int row = 128 + tid / 7;
    int c8 = (tid % 7) * 8;
    bf16x8 v;
#pragma unroll
    for (int j = 0; j < 8; j++) v[j] = (bf16_t)((row == 128) ? 1.0f : 0.0f);
    *(bf16x8*)(&Vlds[row][c8]) = v;
  }

  bf16x8 qf[2][4];
#pragma unroll
  for (int qs = 0; qs < 2; qs++) {
    const int qrow = qt * 128 + wv * 32 + qs * 16 + l15;
#pragma unroll
    for (int kc = 0; kc < 4; kc++)
      qf[qs][kc] = *(const bf16x8*)(Qhb + (size_t)qrow * NINTER + kc * 32 + quad * 8);
  }

  f32x4 o[2][8], ol[2];
#pragma unroll
  for (int qs = 0; qs < 2; qs++) {
#pragma unroll
    for (int dt = 0; dt < 8; dt++)
#pragma unroll
      for (int i = 0; i < 4; i++) o[qs][dt][i] = 0.f;
#pragma unroll
    for (int i = 0; i < 4; i++) ol[qs][i] = 0.f;
  }

  for (int t = 0; t < 32; t++) {
    __syncthreads();
#pragma unroll
    for (int i = 0; i < 2; i++) {          // K tile: 32 rows x 128 d
      int idx = tid + i * 256;
      int row = idx >> 4;
      int c8 = (idx & 15) * 8;
      *(uint4*)(&Klds[row][c8]) =
          *(const uint4*)(Khb + (size_t)(kbase + t * 32 + row) * NINTER + c8);
    }
#pragma unroll
    for (int i = 0; i < 2; i++) {          // V tile: 128 d x 32 m
      int idx = tid + i * 256;
      int row = idx >> 2;
      int c8 = (idx & 3) * 8;
      *(uint4*)(&Vlds[row][c8]) =
          *(const uint4*)(Vb + (size_t)row * HWN + kbase + t * 32 + c8);
    }
    __syncthreads();

    // S^T tiles: s[qs][ks], C col = q (l15), row = key (quad*4+r)
    f32x4 s[2][2];
#pragma unroll
    for (int qs = 0; qs < 2; qs++)
#pragma unroll
      for (int ks = 0; ks < 2; ks++)
#pragma unroll
        for (int i = 0; i < 4; i++) s[qs][ks][i] = 0.f;
#pragma unroll
    for (int ks = 0; ks < 2; ks++)
#pragma unroll
      for (int kc = 0; kc < 4; kc++) {
        bf16x8 kf = *(const bf16x8*)(&Klds[ks * 16 + l15][kc * 32 + quad * 8]);
        s[0][ks] = __builtin_amdgcn_mfma_f32_16x16x32_bf16(kf, qf[0][kc], s[0][ks], 0, 0, 0);
        s[1][ks] = __builtin_amdgcn_mfma_f32_16x16x32_bf16(kf, qf[1][kc], s[1][ks], 0, 0, 0);
      }

    // fixed-max softmax; contiguous bf16x4 P-write per (qs,ks):
    // P[q = qs*16+l15][key = ks*16 + quad*4 + r]
#pragma unroll
    for (int qs = 0; qs < 2; qs++)
#pragma unroll
      for (int ks = 0; ks < 2; ks++) {
        bf16x4 p4;
#pragma unroll
        for (int r = 0; r < 4; r++)
          p4[r] = (bf16_t)fexp2(s[qs][ks][r] - SMAX);
        *(bf16x4*)(&Plds[wv][qs * 16 + l15][ks * 16 + quad * 4]) = p4;
      }

    bf16x8 pf0 = *(const bf16x8*)(&Plds[wv][l15][quad * 8]);
    bf16x8 pf1 = *(const bf16x8*)(&Plds[wv][16 + l15][quad * 8]);
#pragma unroll
    for (int dt = 0; dt < 8; dt++) {
      bf16x8 vf = *(const bf16x8*)(&Vlds[dt * 16 + l15][quad * 8]);
      o[0][dt] = __builtin_amdgcn_mfma_f32_16x16x32_bf16(pf0, vf, o[0][dt], 0, 0, 0);
      o[1][dt] = __builtin_amdgcn_mfma_f32_16x16x32_bf16(pf1, vf, o[1][dt], 0, 0, 0);
    }
    bf16x8 vfl = *(const bf16x8*)(&Vlds[128 + l15][quad * 8]);
    ol[0] = __builtin_amdgcn_mfma_f32_16x16x32_bf16(pf0, vfl, ol[0], 0, 0, 0);
    ol[1] = __builtin_amdgcn_mfma_f32_16x16x32_bf16(pf1, vfl, ol[1], 0, 0, 0);
  }

  float* Ob = Opart + ((size_t)(b * NC + chunk) * HWN) * NINTER;
#pragma unroll
  for (int qs = 0; qs < 2; qs++)
#pragma unroll
    for (int r = 0; r < 4; r++) {
      int n = qt * 128 + wv * 32 + qs * 16 + quad * 4 + r;
#pragma unroll
      for (int dt = 0; dt < 8; dt++)
        Ob[(size_t)n * NINTER + dt * 16 + l15] = o[qs][dt][r];
      if (l15 == 0)
        Lp[(size_t)(b * NC + chunk) * HWN + n] = ol[qs][r];
    }
}

// Fused combine + W conv: sum OP chunks -> normalize -> Y tile in LDS ->
// MFMA -> WY bf16. n-tile 32, grid (128,4).
__global__ __launch_bounds__(256, 4) void wconv_kernel(
    const bf16_t* __restrict__ Wbf, const float* __restrict__ Opart,
    const float* __restrict__ Lp, const float* __restrict__ Wb,
    bf16_t* __restrict__ WY) {
  const int ntb = blockIdx.x;   // 128 tiles of 32 n
  const int b   = blockIdx.y;
  const int tid = threadIdx.x;
  const int lane = tid & 63;
  const int wv   = tid >> 6;
  const int l31  = lane & 31;
  const int half = lane >> 5;

  __shared__ __align__(16) bf16_t Ylds[32][136];
  __shared__ float Linv[32];

  if (tid < 32) {
    int n = ntb * 32 + tid;
    float ls = 0.f;
#pragma unroll
    for (int c = 0; c < NC; c++) ls += Lp[(size_t)(b * NC + c) * HWN + n];
    Linv[tid] = 1.f / ls;
  }

  const int nrow = tid >> 3;
  const int dgrp = tid & 7;
  float oacc[16];
#pragma unroll
  for (int j = 0; j < 16; j++) oacc[j] = 0.f;
#pragma unroll
  for (int c = 0; c < NC; c++) {
    const float* Op = Opart +
        ((size_t)(b * NC + c) * HWN + ntb * 32 + nrow) * NINTER + dgrp * 16;
#pragma unroll
    for (int q = 0; q < 4; q++) {
      f32x4 v = *(const f32x4*)(Op + q * 4);
#pragma unroll
      for (int j = 0; j < 4; j++) oacc[q * 4 + j] += v[j];
    }
  }
  __syncthreads();   // Linv ready
  {
    float inv = Linv[nrow];
    bf16x8 y0, y1;
#pragma unroll
    for (int j = 0; j < 8; j++) {
      y0[j] = (bf16_t)(oacc[j] * inv);
      y1[j] = (bf16_t)(oacc[8 + j] * inv);
    }
    *(bf16x8*)(&Ylds[nrow][dgrp * 16]) = y0;
    *(bf16x8*)(&Ylds[nrow][dgrp * 16 + 8]) = y1;
  }
  __syncthreads();

  const bf16_t* Wh = Wbf + 98304;  // [256][128] hi
  f32x16 acc[2];
#pragma unroll
  for (int c = 0; c < 2; c++)
#pragma unroll
    for (int i = 0; i < 16; i++) acc[c][i] = 0.f;

#pragma unroll
  for (int k0 = 0; k0 < 128; k0 += 16) {
    bf16x8 a0 = *(const bf16x8*)(Wh + (size_t)(wv * 64 + l31) * NINTER + k0 + half * 8);
    bf16x8 a1 = *(const bf16x8*)(Wh + (size_t)(wv * 64 + 32 + l31) * NINTER + k0 + half * 8);
    bf16x8 b0 = *(const bf16x8*)(&Ylds[l31][k0 + half * 8]);
    acc[0] = __builtin_amdgcn_mfma_f32_32x32x16_bf16(a0, b0, acc[0], 0, 0, 0);
    acc[1] = __builtin_amdgcn_mfma_f32_32x32x16_bf16(a1, b0, acc[1], 0, 0, 0);
  }

  bf16_t* dst = WY + (size_t)b * 256 * HWN + ntb * 32;
#pragma unroll
  for (int ct = 0; ct < 2; ct++)
#pragma unroll
    for (int r = 0; r < 16; r++) {
      int co = wv * 64 + ct * 32 + (r & 3) + 8 * (r >> 2) + 4 * half;
      dst[(size_t)co * HWN + l31] = (bf16_t)(acc[ct][r] + Wb[co]);
    }
}

__global__ __launch_bounds__(256) void stats_kernel(
    const bf16_t* __restrict__ WY, float* __restrict__ stats) {
  const int c = blockIdx.x;
  const int tid = threadIdx.x;
  float s = 0.f, s2 = 0.f;
  for (int b = 0; b < NBATCH; b++) {
    const bf16_t* p = WY + ((size_t)b * 256 + c) * HWN;
    for (int i = tid * 8; i < HWN; i += 2048) {
      bf16x8 v8 = *(const bf16x8*)(p + i);
#pragma unroll
      for (int j = 0; j < 8; j++) {
        float v = (float)v8[j];
        s += v;
        s2 += v * v;
      }
    }
  }
#pragma unroll
  for (int off = 1; off < 64; off <<= 1) {
    s += __shfl_xor(s, off);
    s2 += __shfl_xor(s2, off);
  }
  __shared__ float red[8];
  int wv = tid >> 6;
  if ((tid & 63) == 0) { red[wv] = s; red[4 + wv] = s2; }
  __syncthreads();
  if (tid == 0) {
    float S = red[0] + red[1] + red[2] + red[3];
    float S2 = red[4] + red[5] + red[6] + red[7];
    float mean = S * (1.f / 16384.f);
    float var = S2 * (1.f / 16384.f) - mean * mean;
    stats[c] = mean;
    stats[256 + c] = rsqrtf(var + BN_EPS);
  }
}

__global__ __launch_bounds__(256) void bn_kernel(
    const bf16_t* __restrict__ WY, const float* __restrict__ x,
    const float* __restrict__ stats, const float* __restrict__ gamma,
    const float* __restrict__ beta, float* __restrict__ out) {
  int idx = blockIdx.x * 256 + threadIdx.x;
  int e = idx * 4;
  int c = (e >> 12) & 255;
  bf16x4 w4 = *(const bf16x4*)(WY + e);
  float4 xv = *(const float4*)(x + e);
  float mean = stats[c];
  float g = gamma[c] * stats[256 + c];
  float bb = beta[c];
  float4 o;
  o.x = g * ((float)w4[0] - mean) + bb + xv.x;
  o.y = g * ((float)w4[1] - mean) + bb + xv.y;
  o.z = g * ((float)w4[2] - mean) + bb + xv.z;
  o.w = g * ((float)w4[3] - mean) + bb + xv.w;
  *(float4*)(out + e) = o;
}

extern "C" void kernel_launch(void* const* d_in, const int* in_sizes, int n_in,
                              void* d_out, int out_size, void* d_ws, size_t ws_size,
                              hipStream_t stream) {
  const float* x       = (const float*)d_in[0];
  const float* theta_b = (const float*)d_in[2];
  const float* phi_b   = (const float*)d_in[4];
  const float* g_b     = (const float*)d_in[6];
  const float* W_b     = (const float*)d_in[8];
  const float* bn_g    = (const float*)d_in[9];
  const float* bn_b    = (const float*)d_in[10];
  float* out = (float*)d_out;

  char* ws = (char*)d_ws;
  bf16_t* Qh  = (bf16_t*)(ws + OFF_QH);
  bf16_t* Kh  = (bf16_t*)(ws + OFF_KH);
  bf16_t* V   = (bf16_t*)(ws + OFF_V);
  float*  OP  = (float*)(ws + OFF_OP);
  bf16_t* WY  = (bf16_t*)(ws + OFF_WY);
  float*  LP  = (float*)(ws + OFF_LP);
  bf16_t* WBF = (bf16_t*)(ws + OFF_WBF);
  float*  ST  = (float*)(ws + OFF_ST);

  convert_weights<<<512, 256, 0, stream>>>(
      (const float*)d_in[1], (const float*)d_in[3],
      (const float*)d_in[5], (const float*)d_in[7], WBF);
  qkv_kernel<<<dim3(128, NBATCH), 256, 0, stream>>>(
      x, WBF, theta_b, phi_b, g_b, Qh, Kh, V);
  attn_kernel<<<dim3(32, NC, NBATCH), 256, 0, stream>>>(
      Qh, Kh, V, OP, LP);
  wconv_kernel<<<dim3(128, NBATCH), 256, 0, stream>>>(
      WBF, OP, LP, W_b, WY);
  stats_kernel<<<256, 256, 0, stream>>>(WY, ST);
  bn_kernel<<<4096, 256, 0, stream>>>(WY, x, ST, bn_g, bn_b, out);
}